// Round 13
// baseline (227.942 us; speedup 1.0000x reference)
//
#include <hip/hip_runtime.h>
#include <stdint.h>
#include <limits.h>

// StackMachineCell — split design (round 13).
// r12 post-mortem: pure-LDS phase1 works (bank-conflict 0, FETCH gone) but
// 128x256t blocks spread 1/CU -> 1 wave/SIMD -> serial 736 cy/step. With
// <=256 blocks the dispatcher spreads, so waves/block is the ONLY lever on
// contexts/SIMD. This round: 512-thread blocks = 8 waves = 8 chains/block,
// 64 blocks, 104KB LDS (1 block/CU) -> 2 waves/SIMD. 1024t blocks are
// poisoned (r10/r11: VGPR hard-capped to 16). Loop semantics byte-identical
// to r12 (PASSED, absmax 0.0009765625).
// ws: Mm32@0 | Ms32@17408 | Mb32@50176 | traj u16 @115712 (640,000 B).

#define TT 512
#define BB 512
#define HH 128
#define NSs 64
#define NMm 34
#define NBb 128

typedef unsigned short u16;

// i32 max via DPP; old=key, bound_ctrl=false -> disabled source lanes keep key
template <int CTRL, int RMASK>
__device__ __forceinline__ int dppmax(int key) {
  const int t = __builtin_amdgcn_update_dpp(key, key, CTRL, RMASK, 0xf, false);
  return t > key ? t : key;
}

__device__ __forceinline__ int wave_max_i32(int k) {
  k = dppmax<0x111, 0xf>(k);  // row_shr:1
  k = dppmax<0x112, 0xf>(k);  // row_shr:2
  k = dppmax<0x114, 0xf>(k);  // row_shr:4
  k = dppmax<0x118, 0xf>(k);  // row_shr:8
  k = dppmax<0x142, 0xa>(k);  // row_bcast:15
  k = dppmax<0x143, 0xc>(k);  // row_bcast:31
  return __builtin_amdgcn_readlane(k, 63);
}

// ---- precompute M tables (f64 accumulate, f32 store)
__global__ __launch_bounds__(256) void precompute_M(
    const float* __restrict__ embed,
    const float* __restrict__ Wm, const float* __restrict__ bm,
    const float* __restrict__ Wb, const float* __restrict__ bb,
    const float* __restrict__ Ws, const float* __restrict__ bs,
    float* __restrict__ Mm32, float* __restrict__ Ms32,
    float* __restrict__ Mb32) {
  __shared__ double e[HH];
  const int v = blockIdx.x;
  const int tid = threadIdx.x;  // 256
  if (tid < HH) e[tid] = (double)embed[v * HH + tid];
  __syncthreads();
  if (tid < NMm) {
    const int j = tid;
    double acc = 0.0;
    for (int h = 0; h < HH; ++h) acc += e[h] * (double)Wm[h * NMm + j];
    Mm32[v * NMm + j] = (float)(acc + (double)bm[j]);
  } else if (tid < NMm + NSs) {
    const int j = tid - NMm;
    double acc = 0.0;
    for (int h = 0; h < HH; ++h) acc += e[h] * (double)Ws[h * NSs + j];
    Ms32[v * NSs + j] = (float)(acc + (double)bs[j]);
  } else if (tid < NMm + NSs + NBb) {
    const int j = tid - NMm - NSs;
    double acc = 0.0;
    for (int h = 0; h < HH; ++h) acc += e[h] * (double)Wb[h * NBb + j];
    Mb32[v * NBb + j] = (float)(acc + (double)bb[j]);
  }
}

// ---- phase 1: trajectory only, pure-LDS inner loop.
// 64 blocks x 512 threads (8 waves = 8 chains). 104KB LDS -> 1 block/CU,
// 2 waves/SIMD (r12 was 1/SIMD — the bottleneck).
__global__ __launch_bounds__(512, 1) void sm_phase1(
    const int* __restrict__ x, const int* __restrict__ tact,
    const int* __restrict__ tstate, const int* __restrict__ forc,
    const float* __restrict__ Wm, const float* __restrict__ Ws,
    const float* __restrict__ Mm32g, const float* __restrict__ Ms32g,
    u16* __restrict__ traj) {
  __shared__ float sMm[128 * NMm];     // 17408 B
  __shared__ float sMs[128 * NSs];     // 32768 B
  __shared__ float sWm[96 * NMm];      // 13056 B
  __shared__ float sWs[96 * NSs];      // 24576 B
  __shared__ unsigned int sPk[8][TT];  // 16384 B  -> 104192 B total
  const int tid = threadIdx.x;
  const int base = blockIdx.x * 8;
  for (int i = tid; i < 128 * NMm; i += 512) sMm[i] = Mm32g[i];
  for (int i = tid; i < 128 * NSs; i += 512) sMs[i] = Ms32g[i];
  for (int i = tid; i < 96 * NMm; i += 512) sWm[i] = Wm[128 * NMm + i];
  for (int i = tid; i < 96 * NSs; i += 512) sWs[i] = Ws[128 * NSs + i];
  for (int i = tid; i < 8 * TT; i += 512) {
    const int w = i >> 9, t = i & (TT - 1);
    const int g = t * BB + base + w;
    sPk[w][t] = (unsigned)x[g] | ((unsigned)tact[g] << 8) |
                ((unsigned)tstate[g] << 16) | ((unsigned)forc[g] << 24);
  }
  __syncthreads();

  const int lane = tid & 63;
  const int w = tid >> 6;
  const int b = base + w;
  const int lane34 = (lane < NMm) ? lane : 0;

  int stackv = 0;  // lane i holds stack[i]
  int ptr = 0, r = 0, s = 0;

  // packed-int prefetch pipeline (LDS, input-only, 3 ahead)
  unsigned p0 = sPk[w][0], p1 = sPk[w][1], p2 = sPk[w][2];

  for (int t = 0; t < TT; ++t) {
    const unsigned p3 = sPk[w][t + 3 < TT ? t + 3 : TT - 1];
    const unsigned pk = __builtin_amdgcn_readfirstlane(p0);

    // record carry-in (s,r) — phase 2 consumes
    if (lane == 0) traj[t * BB + b] = (u16)(s | (r << 8));

    int act, ns;
    if (pk >> 24) {  // forced: nothing to compute
      act = (pk >> 8) & 63;
      ns = (pk >> 16) & 63;
    } else {
      const int v = pk & 127;
      // 6 parallel LDS reads; f64 sums (exact for f32 inputs)
      const float mmv = sMm[v * NMm + lane34];
      const float wms = sWm[s * NMm + lane34];
      const float wmr = sWm[(64 + r) * NMm + lane34];
      const float msv = sMs[v * NSs + lane];
      const float wss = sWs[s * NSs + lane];
      const float wsr = sWs[(64 + r) * NSs + lane];
      const double lm = (double)mmv + (double)wms + (double)wmr;
      const double lsv = (double)msv + (double)wss + (double)wsr;
      // i32 keys, scale 2^26 (|logit|<0.5): trunc monotone, gap-safe (r4/r12)
      const int ivm = (int)(lm * 67108864.0);
      const int ivs = (int)(lsv * 67108864.0);
      int km = (lane < NMm)
                   ? (int)(((unsigned)ivm << 6) | (unsigned)(63 - lane))
                   : INT_MIN;
      int ks = (int)(((unsigned)ivs << 6) | (unsigned)(63 - lane));
      km = wave_max_i32(km);
      ks = wave_max_i32(ks);
      act = 63 - (km & 63);
      ns = 63 - (ks & 63);
    }

    const bool ispush = act >= 2;
    int npn = ptr + (ispush ? 1 : 0) - (act == 1 ? 1 : 0);
    npn = npn < 0 ? 0 : (npn > 63 ? 63 : npn);
    if (ispush && lane == npn) stackv = act - 2;
    r = __builtin_amdgcn_readlane(stackv, npn);
    ptr = npn;
    s = ns;

    p0 = p1; p1 = p2; p2 = p3;
  }
}

// ---- phase 2: materialize all logits. One row (t,b) per wave-iteration.
__global__ __launch_bounds__(256) void sm_phase2(
    const int* __restrict__ x, const u16* __restrict__ traj,
    const float* __restrict__ Wm, const float* __restrict__ Wb,
    const float* __restrict__ Ws,
    const float* __restrict__ Mm32, const float* __restrict__ Ms32,
    const float* __restrict__ Mb32, float* __restrict__ out) {
  const int tid = threadIdx.x;
  const int lane = tid & 63;
  const int wid = blockIdx.x * 4 + (tid >> 6);   // 2048 blocks -> 8192 waves
  float* outLM = out;                                  // [T,B,34]
  float* outLB = out + (size_t)TT * BB * NMm;          // [T,B,128]
  float* outLS = out + (size_t)TT * BB * (NMm + NBb);  // [T,B,64]

  for (int row = wid; row < TT * BB; row += 8192) {
    const int xv = x[row];          // wave-uniform -> scalar load
    const int pr = traj[row];
    const int s = pr & 255;
    const int r = pr >> 8;
    const int rs = 128 + s, rr = 192 + r;
    if (lane < NMm)
      outLM[(size_t)row * NMm + lane] =
          Mm32[xv * NMm + lane] + Wm[rs * NMm + lane] + Wm[rr * NMm + lane];
    outLS[(size_t)row * NSs + lane] =
        Ms32[xv * NSs + lane] + Ws[rs * NSs + lane] + Ws[rr * NSs + lane];
    outLB[(size_t)row * NBb + lane] =
        Mb32[xv * NBb + lane] + Wb[rs * NBb + lane] + Wb[rr * NBb + lane];
    outLB[(size_t)row * NBb + 64 + lane] =
        Mb32[xv * NBb + 64 + lane] + Wb[rs * NBb + 64 + lane] +
        Wb[rr * NBb + 64 + lane];
  }
}

extern "C" void kernel_launch(void* const* d_in, const int* in_sizes, int n_in,
                              void* d_out, int out_size, void* d_ws, size_t ws_size,
                              hipStream_t stream) {
  const int* x     = (const int*)d_in[0];
  const int* tactp = (const int*)d_in[1];
  const int* tstp  = (const int*)d_in[2];
  const int* forcp = (const int*)d_in[3];
  const float* embed = (const float*)d_in[4];
  const float* Wm = (const float*)d_in[5];
  const float* bm = (const float*)d_in[6];
  const float* Wb = (const float*)d_in[7];
  const float* bb = (const float*)d_in[8];
  const float* Ws = (const float*)d_in[9];
  const float* bs = (const float*)d_in[10];

  char* wsp = (char*)d_ws;
  float* Mm32 = (float*)(wsp);            //  17408 B
  float* Ms32 = (float*)(wsp + 17408);    //  32768 B
  float* Mb32 = (float*)(wsp + 50176);    //  65536 B
  u16*   traj = (u16*)(wsp + 115712);     // 524288 B -> total 640000 B

  precompute_M<<<128, 256, 0, stream>>>(embed, Wm, bm, Wb, bb, Ws, bs,
                                        Mm32, Ms32, Mb32);
  sm_phase1<<<64, 512, 0, stream>>>(x, tactp, tstp, forcp, Wm, Ws,
                                    Mm32, Ms32, traj);
  sm_phase2<<<2048, 256, 0, stream>>>(x, traj, Wm, Wb, Ws,
                                      Mm32, Ms32, Mb32, (float*)d_out);
}

// Round 14
// 209.876 us; speedup vs baseline: 1.0861x; 1.0861x over previous
//
#include <hip/hip_runtime.h>
#include <stdint.h>
#include <limits.h>

// StackMachineCell — LUT design (round 14).
// r13 falsified the occupancy theory: 512 chains < 1024 SIMDs, so wall time
// == single-chain step latency; waves/SIMD is irrelevant. Attack the chain:
// (act,ns) depends only on (v,s,r) in 128x64x32=256K combos -> precompute a
// decision LUT in parallel (bit-identical arithmetic to the r12/r13 passing
// trajectory: same add order, same 2^26 i32 quantization, same first-index
// tie-break). Phase1 non-forced step = one uniform u16 L2 load + stack
// update; traj stores leave the chain (lane-rotated capture, one coalesced
// store per 64 steps, [b][t] layout; phase2 reindexed).
// ws: Mm32@0 | Ms32@17408 | Mb32@50176 | LUT u16 @115712 | traj u16 @640000
// (total 1164288 B; guarded).

#define TT 512
#define BB 512
#define HH 128
#define NSs 64
#define NMm 34
#define NBb 128

typedef unsigned short u16;

// ---- precompute M tables (f64 accumulate, f32 store)
__global__ __launch_bounds__(256) void precompute_M(
    const float* __restrict__ embed,
    const float* __restrict__ Wm, const float* __restrict__ bm,
    const float* __restrict__ Wb, const float* __restrict__ bb,
    const float* __restrict__ Ws, const float* __restrict__ bs,
    float* __restrict__ Mm32, float* __restrict__ Ms32,
    float* __restrict__ Mb32) {
  __shared__ double e[HH];
  const int v = blockIdx.x;
  const int tid = threadIdx.x;  // 256
  if (tid < HH) e[tid] = (double)embed[v * HH + tid];
  __syncthreads();
  if (tid < NMm) {
    const int j = tid;
    double acc = 0.0;
    for (int h = 0; h < HH; ++h) acc += e[h] * (double)Wm[h * NMm + j];
    Mm32[v * NMm + j] = (float)(acc + (double)bm[j]);
  } else if (tid < NMm + NSs) {
    const int j = tid - NMm;
    double acc = 0.0;
    for (int h = 0; h < HH; ++h) acc += e[h] * (double)Ws[h * NSs + j];
    Ms32[v * NSs + j] = (float)(acc + (double)bs[j]);
  } else if (tid < NMm + NSs + NBb) {
    const int j = tid - NMm - NSs;
    double acc = 0.0;
    for (int h = 0; h < HH; ++h) acc += e[h] * (double)Wb[h * NBb + j];
    Mb32[v * NBb + j] = (float)(acc + (double)bb[j]);
  }
}

// ---- build decision LUT: block = (s,r) pair, thread = v.
// Arithmetic bit-identical to r12's passing loop: ((f64)M + (f64)W_s) +
// (f64)W_r, quantize (int)(val*2^26), strict-> first-index argmax.
__global__ __launch_bounds__(128) void build_lut(
    const float* __restrict__ Wm, const float* __restrict__ Ws,
    const float* __restrict__ Mm32g, const float* __restrict__ Ms32g,
    u16* __restrict__ lut) {
  __shared__ float sMm[128 * NMm];  // 17408 B
  __shared__ float sMs[128 * NSs];  // 32768 B
  __shared__ float wms[NMm], wmr[NMm], wss[NSs], wsr[NSs];  // 784 B
  const int s = blockIdx.x >> 5;    // 0..63
  const int r = blockIdx.x & 31;    // 0..31
  const int tid = threadIdx.x;      // 128
  for (int i = tid; i < 128 * NMm; i += 128) sMm[i] = Mm32g[i];
  for (int i = tid; i < 128 * NSs; i += 128) sMs[i] = Ms32g[i];
  if (tid < NMm) {
    wms[tid] = Wm[(128 + s) * NMm + tid];
    wmr[tid] = Wm[(192 + r) * NMm + tid];
  }
  if (tid < NSs) {
    wss[tid] = Ws[(128 + s) * NSs + tid];
    wsr[tid] = Ws[(192 + r) * NSs + tid];
  }
  __syncthreads();

  const int v = tid;  // one v per thread
  int bestm = INT_MIN, act = 0;
#pragma unroll
  for (int j = 0; j < NMm; ++j) {
    const double val = (double)sMm[v * NMm + j] + (double)wms[j] + (double)wmr[j];
    const int iv = (int)(val * 67108864.0);
    if (iv > bestm) { bestm = iv; act = j; }
  }
  int bests = INT_MIN, ns = 0;
#pragma unroll
  for (int j = 0; j < NSs; ++j) {
    const double val = (double)sMs[v * NSs + j] + (double)wss[j] + (double)wsr[j];
    const int iv = (int)(val * 67108864.0);
    if (iv > bests) { bests = iv; ns = j; }
  }
  lut[(unsigned)blockIdx.x * 128 + v] = (u16)(act | (ns << 6));
}

// ---- phase 1: trajectory via LUT. 128 blocks x 256 threads (4 chains/blk).
// Non-forced step = one uniform L2 u16 load + stack update. Traj captured
// lane-rotated, stored coalesced every 64 steps in [b][t] layout.
__global__ __launch_bounds__(256) void sm_phase1(
    const int* __restrict__ x, const int* __restrict__ tact,
    const int* __restrict__ tstate, const int* __restrict__ forc,
    const u16* __restrict__ lut, u16* __restrict__ traj) {
  __shared__ unsigned int sPk[4][TT];  // 8192 B
  const int tid = threadIdx.x;
  const int base = blockIdx.x * 4;
  for (int i = tid; i < 4 * TT; i += 256) {
    const int w = i >> 9, t = i & (TT - 1);
    const int g = t * BB + base + w;
    sPk[w][t] = (unsigned)x[g] | ((unsigned)tact[g] << 8) |
                ((unsigned)tstate[g] << 16) | ((unsigned)forc[g] << 24);
  }
  __syncthreads();

  const int lane = tid & 63;
  const int w = tid >> 6;
  const int b = base + w;

  int stackv = 0;  // lane i holds stack[i]
  int ptr = 0, r = 0, s = 0;
  int myv = 0;     // lane-rotated traj capture

  unsigned p0 = sPk[w][0], p1 = sPk[w][1], p2 = sPk[w][2];

  for (int t = 0; t < TT; ++t) {
    const unsigned p3 = sPk[w][t + 3 < TT ? t + 3 : TT - 1];
    const unsigned pk = __builtin_amdgcn_readfirstlane(p0);

    // capture carry-in (s,r) into lane (t&63); store every 64 steps
    const int cur = s | (r << 8);
    if (lane == (t & 63)) myv = cur;

    int act, ns;
    if (pk >> 24) {  // forced: no lookup needed
      act = (pk >> 8) & 63;
      ns = (pk >> 16) & 63;
    } else {
      const unsigned idx = (unsigned)((s * 32 + r) * 128) + (pk & 127);
      const int lv = lut[idx];  // uniform address -> L2 (~225cy), the chain
      act = lv & 63;
      ns = (lv >> 6) & 63;
      act = __builtin_amdgcn_readfirstlane(act);
      ns = __builtin_amdgcn_readfirstlane(ns);
    }

    const bool ispush = act >= 2;
    int npn = ptr + (ispush ? 1 : 0) - (act == 1 ? 1 : 0);
    npn = npn < 0 ? 0 : (npn > 63 ? 63 : npn);
    if (ispush && lane == npn) stackv = act - 2;
    r = __builtin_amdgcn_readlane(stackv, npn);
    ptr = npn;
    s = ns;

    if ((t & 63) == 63)  // coalesced 128B store per wave, off-chain
      traj[b * TT + (t & ~63) + lane] = (u16)myv;

    p0 = p1; p1 = p2; p2 = p3;
  }
}

// ---- phase 2: materialize all logits. One row (t,b) per wave-iteration.
// traj is [b][t] (round-14 layout change).
__global__ __launch_bounds__(256) void sm_phase2(
    const int* __restrict__ x, const u16* __restrict__ traj,
    const float* __restrict__ Wm, const float* __restrict__ Wb,
    const float* __restrict__ Ws,
    const float* __restrict__ Mm32, const float* __restrict__ Ms32,
    const float* __restrict__ Mb32, float* __restrict__ out) {
  const int tid = threadIdx.x;
  const int lane = tid & 63;
  const int wid = blockIdx.x * 4 + (tid >> 6);   // 2048 blocks -> 8192 waves
  float* outLM = out;                                  // [T,B,34]
  float* outLB = out + (size_t)TT * BB * NMm;          // [T,B,128]
  float* outLS = out + (size_t)TT * BB * (NMm + NBb);  // [T,B,64]

  for (int row = wid; row < TT * BB; row += 8192) {
    const int t = row >> 9;
    const int b = row & (BB - 1);
    const int xv = x[row];            // wave-uniform -> scalar load
    const int pr = traj[b * TT + t];
    const int s = pr & 255;
    const int r = pr >> 8;
    const int rs = 128 + s, rr = 192 + r;
    if (lane < NMm)
      outLM[(size_t)row * NMm + lane] =
          Mm32[xv * NMm + lane] + Wm[rs * NMm + lane] + Wm[rr * NMm + lane];
    outLS[(size_t)row * NSs + lane] =
        Ms32[xv * NSs + lane] + Ws[rs * NSs + lane] + Ws[rr * NSs + lane];
    outLB[(size_t)row * NBb + lane] =
        Mb32[xv * NBb + lane] + Wb[rs * NBb + lane] + Wb[rr * NBb + lane];
    outLB[(size_t)row * NBb + 64 + lane] =
        Mb32[xv * NBb + 64 + lane] + Wb[rs * NBb + 64 + lane] +
        Wb[rr * NBb + 64 + lane];
  }
}

extern "C" void kernel_launch(void* const* d_in, const int* in_sizes, int n_in,
                              void* d_out, int out_size, void* d_ws, size_t ws_size,
                              hipStream_t stream) {
  if (ws_size < 1164288) return;  // signature: absmax 0.3457 -> ws too small

  const int* x     = (const int*)d_in[0];
  const int* tactp = (const int*)d_in[1];
  const int* tstp  = (const int*)d_in[2];
  const int* forcp = (const int*)d_in[3];
  const float* embed = (const float*)d_in[4];
  const float* Wm = (const float*)d_in[5];
  const float* bm = (const float*)d_in[6];
  const float* Wb = (const float*)d_in[7];
  const float* bb = (const float*)d_in[8];
  const float* Ws = (const float*)d_in[9];
  const float* bs = (const float*)d_in[10];

  char* wsp = (char*)d_ws;
  float* Mm32 = (float*)(wsp);            //  17408 B
  float* Ms32 = (float*)(wsp + 17408);    //  32768 B
  float* Mb32 = (float*)(wsp + 50176);    //  65536 B
  u16*   lut  = (u16*)(wsp + 115712);     // 524288 B
  u16*   traj = (u16*)(wsp + 640000);     // 524288 B -> total 1164288 B

  precompute_M<<<128, 256, 0, stream>>>(embed, Wm, bm, Wb, bb, Ws, bs,
                                        Mm32, Ms32, Mb32);
  build_lut<<<2048, 128, 0, stream>>>(Wm, Ws, Mm32, Ms32, lut);
  sm_phase1<<<128, 256, 0, stream>>>(x, tactp, tstp, forcp, lut, traj);
  sm_phase2<<<2048, 256, 0, stream>>>(x, traj, Wm, Wb, Ws,
                                      Mm32, Ms32, Mb32, (float*)d_out);
}

// Round 15
// 203.128 us; speedup vs baseline: 1.1222x; 1.0332x over previous
//
#include <hip/hip_runtime.h>
#include <stdint.h>
#include <limits.h>

// StackMachineCell — LUT design (round 15).
// r14 accounting: no kernel >134us but e2e only -6; suspects: (1) build_lut's
// pointless 50KB LDS staging (threads only need their own v-row; staging loop
// is vmcnt-chained and caps residency at 3 blocks/CU) -> read L2 direct;
// (2) phase1's fully-scalar LUT index -> SMEM load sharing lgkmcnt with sPk
// ds_reads (r6 pathology) -> force vector path via opaque v_mov;
// (3) phase2: 2x TLP (4096 blocks, contiguous rows) + float2 on the Wb/Mb
// half of traffic. All changes value-preserving; absmax must stay 0.0009765625.
// ws: Mm32@0 | Ms32@17408 | Mb32@50176 | LUT u16 @115712 | traj u16 @640000
// (total 1164288 B; guarded).

#define TT 512
#define BB 512
#define HH 128
#define NSs 64
#define NMm 34
#define NBb 128

typedef unsigned short u16;
typedef float f2 __attribute__((ext_vector_type(2)));

// ---- precompute M tables (f64 accumulate, f32 store)
__global__ __launch_bounds__(256) void precompute_M(
    const float* __restrict__ embed,
    const float* __restrict__ Wm, const float* __restrict__ bm,
    const float* __restrict__ Wb, const float* __restrict__ bb,
    const float* __restrict__ Ws, const float* __restrict__ bs,
    float* __restrict__ Mm32, float* __restrict__ Ms32,
    float* __restrict__ Mb32) {
  __shared__ double e[HH];
  const int v = blockIdx.x;
  const int tid = threadIdx.x;  // 256
  if (tid < HH) e[tid] = (double)embed[v * HH + tid];
  __syncthreads();
  if (tid < NMm) {
    const int j = tid;
    double acc = 0.0;
    for (int h = 0; h < HH; ++h) acc += e[h] * (double)Wm[h * NMm + j];
    Mm32[v * NMm + j] = (float)(acc + (double)bm[j]);
  } else if (tid < NMm + NSs) {
    const int j = tid - NMm;
    double acc = 0.0;
    for (int h = 0; h < HH; ++h) acc += e[h] * (double)Ws[h * NSs + j];
    Ms32[v * NSs + j] = (float)(acc + (double)bs[j]);
  } else if (tid < NMm + NSs + NBb) {
    const int j = tid - NMm - NSs;
    double acc = 0.0;
    for (int h = 0; h < HH; ++h) acc += e[h] * (double)Wb[h * NBb + j];
    Mb32[v * NBb + j] = (float)(acc + (double)bb[j]);
  }
}

// ---- build decision LUT: block = (s,r) pair, thread = v. NO table staging:
// each thread reads only its own v-row straight from L2. Arithmetic
// bit-identical to r12-r14: ((f64)M + (f64)W_s) + (f64)W_r, (int)(val*2^26),
// strict-> first-index argmax.
__global__ __launch_bounds__(128) void build_lut(
    const float* __restrict__ Wm, const float* __restrict__ Ws,
    const float* __restrict__ Mm32g, const float* __restrict__ Ms32g,
    u16* __restrict__ lut) {
  __shared__ float wms[NMm], wmr[NMm], wss[NSs], wsr[NSs];  // 784 B
  const int s = blockIdx.x >> 5;    // 0..63
  const int r = blockIdx.x & 31;    // 0..31
  const int tid = threadIdx.x;      // 128 = one v per thread
  if (tid < NMm) {
    wms[tid] = Wm[(128 + s) * NMm + tid];
    wmr[tid] = Wm[(192 + r) * NMm + tid];
  }
  if (tid < NSs) {
    wss[tid] = Ws[(128 + s) * NSs + tid];
    wsr[tid] = Ws[(192 + r) * NSs + tid];
  }
  __syncthreads();

  const int v = tid;
  int bestm = INT_MIN, act = 0;
#pragma unroll
  for (int j = 0; j < NMm; ++j) {
    const double val = (double)Mm32g[v * NMm + j] + (double)wms[j] + (double)wmr[j];
    const int iv = (int)(val * 67108864.0);
    if (iv > bestm) { bestm = iv; act = j; }
  }
  int bests = INT_MIN, ns = 0;
#pragma unroll
  for (int j = 0; j < NSs; ++j) {
    const double val = (double)Ms32g[v * NSs + j] + (double)wss[j] + (double)wsr[j];
    const int iv = (int)(val * 67108864.0);
    if (iv > bests) { bests = iv; ns = j; }
  }
  lut[(unsigned)blockIdx.x * 128 + v] = (u16)(act | (ns << 6));
}

// ---- phase 1: trajectory via LUT. 128 blocks x 256 threads (4 chains/blk).
// LUT lookup forced onto the VECTOR path (vmcnt) so it can't entangle with
// the sPk ds_reads on lgkmcnt (r6 lesson).
__global__ __launch_bounds__(256) void sm_phase1(
    const int* __restrict__ x, const int* __restrict__ tact,
    const int* __restrict__ tstate, const int* __restrict__ forc,
    const u16* __restrict__ lut, u16* __restrict__ traj) {
  __shared__ unsigned int sPk[4][TT];  // 8192 B
  const int tid = threadIdx.x;
  const int base = blockIdx.x * 4;
  for (int i = tid; i < 4 * TT; i += 256) {
    const int w = i >> 9, t = i & (TT - 1);
    const int g = t * BB + base + w;
    sPk[w][t] = (unsigned)x[g] | ((unsigned)tact[g] << 8) |
                ((unsigned)tstate[g] << 16) | ((unsigned)forc[g] << 24);
  }
  __syncthreads();

  const int lane = tid & 63;
  const int w = tid >> 6;
  const int b = base + w;

  int stackv = 0;  // lane i holds stack[i]
  int ptr = 0, r = 0, s = 0;
  int myv = 0;     // lane-rotated traj capture

  unsigned p0 = sPk[w][0], p1 = sPk[w][1], p2 = sPk[w][2];

  for (int t = 0; t < TT; ++t) {
    const unsigned p3 = sPk[w][t + 3 < TT ? t + 3 : TT - 1];
    const unsigned pk = __builtin_amdgcn_readfirstlane(p0);

    // capture carry-in (s,r) into lane (t&63); store every 64 steps
    const int cur = s | (r << 8);
    if (lane == (t & 63)) myv = cur;

    int act, ns;
    if (pk >> 24) {  // forced: no lookup needed
      act = (pk >> 8) & 63;
      ns = (pk >> 16) & 63;
    } else {
      int li;
      asm("v_mov_b32 %0, %1"
          : "=v"(li)
          : "r"((int)((s * 32 + r) * 128) + (int)(pk & 127)));
      const int lv = lut[li];  // vector load, vmcnt-tracked, L2-hot
      act = __builtin_amdgcn_readfirstlane(lv & 63);
      ns = __builtin_amdgcn_readfirstlane((lv >> 6) & 63);
    }

    const bool ispush = act >= 2;
    int npn = ptr + (ispush ? 1 : 0) - (act == 1 ? 1 : 0);
    npn = npn < 0 ? 0 : (npn > 63 ? 63 : npn);
    if (ispush && lane == npn) stackv = act - 2;
    r = __builtin_amdgcn_readlane(stackv, npn);
    ptr = npn;
    s = ns;

    if ((t & 63) == 63)  // coalesced 128B store per wave, off-chain
      traj[b * TT + (t & ~63) + lane] = (u16)myv;

    p0 = p1; p1 = p2; p2 = p3;
  }
}

// ---- phase 2: materialize all logits. 4096 blocks x 256t = 16384 waves,
// 16 contiguous rows per wave. Wb/Mb half as float2 (bit-identical sums).
__global__ __launch_bounds__(256) void sm_phase2(
    const int* __restrict__ x, const u16* __restrict__ traj,
    const float* __restrict__ Wm, const float* __restrict__ Wb,
    const float* __restrict__ Ws,
    const float* __restrict__ Mm32, const float* __restrict__ Ms32,
    const float* __restrict__ Mb32, float* __restrict__ out) {
  const int tid = threadIdx.x;
  const int lane = tid & 63;
  const int wid = blockIdx.x * 4 + (tid >> 6);   // 16384 waves
  float* outLM = out;                                  // [T,B,34]
  float* outLB = out + (size_t)TT * BB * NMm;          // [T,B,128]
  float* outLS = out + (size_t)TT * BB * (NMm + NBb);  // [T,B,64]

  const int row0 = wid * 16;
#pragma unroll 2
  for (int k = 0; k < 16; ++k) {
    const int row = row0 + k;
    const int t = row >> 9;
    const int b = row & (BB - 1);
    const int xv = x[row];            // wave-uniform -> scalar load
    const int pr = traj[b * TT + t];
    const int s = pr & 255;
    const int r = pr >> 8;
    const int rs = 128 + s, rr = 192 + r;
    if (lane < NMm)
      outLM[(size_t)row * NMm + lane] =
          Mm32[xv * NMm + lane] + Wm[rs * NMm + lane] + Wm[rr * NMm + lane];
    outLS[(size_t)row * NSs + lane] =
        Ms32[xv * NSs + lane] + Ws[rs * NSs + lane] + Ws[rr * NSs + lane];
    const f2 mb  = *(const f2*)&Mb32[xv * NBb + 2 * lane];
    const f2 wbs = *(const f2*)&Wb[rs * NBb + 2 * lane];
    const f2 wbr = *(const f2*)&Wb[rr * NBb + 2 * lane];
    f2 o;
    o.x = mb.x + wbs.x + wbr.x;   // same per-element add order as before
    o.y = mb.y + wbs.y + wbr.y;
    *(f2*)&outLB[(size_t)row * NBb + 2 * lane] = o;
  }
}

extern "C" void kernel_launch(void* const* d_in, const int* in_sizes, int n_in,
                              void* d_out, int out_size, void* d_ws, size_t ws_size,
                              hipStream_t stream) {
  if (ws_size < 1164288) return;  // signature: absmax 0.3457 -> ws too small

  const int* x     = (const int*)d_in[0];
  const int* tactp = (const int*)d_in[1];
  const int* tstp  = (const int*)d_in[2];
  const int* forcp = (const int*)d_in[3];
  const float* embed = (const float*)d_in[4];
  const float* Wm = (const float*)d_in[5];
  const float* bm = (const float*)d_in[6];
  const float* Wb = (const float*)d_in[7];
  const float* bb = (const float*)d_in[8];
  const float* Ws = (const float*)d_in[9];
  const float* bs = (const float*)d_in[10];

  char* wsp = (char*)d_ws;
  float* Mm32 = (float*)(wsp);            //  17408 B
  float* Ms32 = (float*)(wsp + 17408);    //  32768 B
  float* Mb32 = (float*)(wsp + 50176);    //  65536 B
  u16*   lut  = (u16*)(wsp + 115712);     // 524288 B
  u16*   traj = (u16*)(wsp + 640000);     // 524288 B -> total 1164288 B

  precompute_M<<<128, 256, 0, stream>>>(embed, Wm, bm, Wb, bb, Ws, bs,
                                        Mm32, Ms32, Mb32);
  build_lut<<<2048, 128, 0, stream>>>(Wm, Ws, Mm32, Ms32, lut);
  sm_phase1<<<128, 256, 0, stream>>>(x, tactp, tstp, forcp, lut, traj);
  sm_phase2<<<4096, 256, 0, stream>>>(x, traj, Wm, Wb, Ws,
                                      Mm32, Ms32, Mb32, (float*)d_out);
}

// Round 16
// 201.342 us; speedup vs baseline: 1.1321x; 1.0089x over previous
//
#include <hip/hip_runtime.h>
#include <stdint.h>
#include <limits.h>

// StackMachineCell — LUT design (round 16).
// r15 post-mortem: build_lut's direct v-row reads are stride-136/256B ->
// every wave-load touches ~64 cache lines (4KB L2 traffic per 256B useful).
// Fix 1: precompute also writes TRANSPOSED MmT[34][128]/MsT[64][128]; at
// iter j lanes v=0..127 read consecutive -> coalesced, bit-identical values.
// Fix 2: traj back to [t][b]: phase1's store is off-chain (scatter ok, 8
// insts/chain), phase2's read becomes 32B contiguous per wave-iteration.
// All changes value-preserving; absmax must stay 0.0009765625.
// ws: Mm32@0 | Ms32@17408 | Mb32@50176 | MmT@115712 | MsT@133120 |
//     lut@165888 | traj@690176  (total 1214464 B; guarded).

#define TT 512
#define BB 512
#define HH 128
#define NSs 64
#define NMm 34
#define NBb 128

typedef unsigned short u16;
typedef float f2 __attribute__((ext_vector_type(2)));

// ---- precompute M tables (f64 accumulate, f32 store; + transposed copies)
__global__ __launch_bounds__(256) void precompute_M(
    const float* __restrict__ embed,
    const float* __restrict__ Wm, const float* __restrict__ bm,
    const float* __restrict__ Wb, const float* __restrict__ bb,
    const float* __restrict__ Ws, const float* __restrict__ bs,
    float* __restrict__ Mm32, float* __restrict__ Ms32,
    float* __restrict__ Mb32, float* __restrict__ MmT,
    float* __restrict__ MsT) {
  __shared__ double e[HH];
  const int v = blockIdx.x;
  const int tid = threadIdx.x;  // 256
  if (tid < HH) e[tid] = (double)embed[v * HH + tid];
  __syncthreads();
  if (tid < NMm) {
    const int j = tid;
    double acc = 0.0;
    for (int h = 0; h < HH; ++h) acc += e[h] * (double)Wm[h * NMm + j];
    const float r = (float)(acc + (double)bm[j]);
    Mm32[v * NMm + j] = r;
    MmT[j * 128 + v] = r;
  } else if (tid < NMm + NSs) {
    const int j = tid - NMm;
    double acc = 0.0;
    for (int h = 0; h < HH; ++h) acc += e[h] * (double)Ws[h * NSs + j];
    const float r = (float)(acc + (double)bs[j]);
    Ms32[v * NSs + j] = r;
    MsT[j * 128 + v] = r;
  } else if (tid < NMm + NSs + NBb) {
    const int j = tid - NMm - NSs;
    double acc = 0.0;
    for (int h = 0; h < HH; ++h) acc += e[h] * (double)Wb[h * NBb + j];
    Mb32[v * NBb + j] = (float)(acc + (double)bb[j]);
  }
}

// ---- build decision LUT: block = (s,r) pair, thread = v. Coalesced reads
// from transposed tables; arithmetic bit-identical to r12-r15:
// ((f64)M + (f64)W_s) + (f64)W_r, (int)(val*2^26), strict-> first-index.
__global__ __launch_bounds__(128) void build_lut(
    const float* __restrict__ Wm, const float* __restrict__ Ws,
    const float* __restrict__ MmT, const float* __restrict__ MsT,
    u16* __restrict__ lut) {
  __shared__ float wms[NMm], wmr[NMm], wss[NSs], wsr[NSs];  // 784 B
  const int s = blockIdx.x >> 5;    // 0..63
  const int r = blockIdx.x & 31;    // 0..31
  const int tid = threadIdx.x;      // 128 = one v per thread
  if (tid < NMm) {
    wms[tid] = Wm[(128 + s) * NMm + tid];
    wmr[tid] = Wm[(192 + r) * NMm + tid];
  }
  if (tid < NSs) {
    wss[tid] = Ws[(128 + s) * NSs + tid];
    wsr[tid] = Ws[(192 + r) * NSs + tid];
  }
  __syncthreads();

  const int v = tid;
  int bestm = INT_MIN, act = 0;
#pragma unroll
  for (int j = 0; j < NMm; ++j) {
    const double val = (double)MmT[j * 128 + v] + (double)wms[j] + (double)wmr[j];
    const int iv = (int)(val * 67108864.0);
    if (iv > bestm) { bestm = iv; act = j; }
  }
  int bests = INT_MIN, ns = 0;
#pragma unroll
  for (int j = 0; j < NSs; ++j) {
    const double val = (double)MsT[j * 128 + v] + (double)wss[j] + (double)wsr[j];
    const int iv = (int)(val * 67108864.0);
    if (iv > bests) { bests = iv; ns = j; }
  }
  lut[(unsigned)blockIdx.x * 128 + v] = (u16)(act | (ns << 6));
}

// ---- phase 1: trajectory via LUT. 128 blocks x 256 threads (4 chains/blk).
// LUT lookup on the VECTOR path (vmcnt; r6 lesson). traj in [t][b]:
// scatter-store every 64 steps is off-chain (8 insts total per chain).
__global__ __launch_bounds__(256) void sm_phase1(
    const int* __restrict__ x, const int* __restrict__ tact,
    const int* __restrict__ tstate, const int* __restrict__ forc,
    const u16* __restrict__ lut, u16* __restrict__ traj) {
  __shared__ unsigned int sPk[4][TT];  // 8192 B
  const int tid = threadIdx.x;
  const int base = blockIdx.x * 4;
  for (int i = tid; i < 4 * TT; i += 256) {
    const int w = i >> 9, t = i & (TT - 1);
    const int g = t * BB + base + w;
    sPk[w][t] = (unsigned)x[g] | ((unsigned)tact[g] << 8) |
                ((unsigned)tstate[g] << 16) | ((unsigned)forc[g] << 24);
  }
  __syncthreads();

  const int lane = tid & 63;
  const int w = tid >> 6;
  const int b = base + w;

  int stackv = 0;  // lane i holds stack[i]
  int ptr = 0, r = 0, s = 0;
  int myv = 0;     // lane-rotated traj capture

  unsigned p0 = sPk[w][0], p1 = sPk[w][1], p2 = sPk[w][2];

  for (int t = 0; t < TT; ++t) {
    const unsigned p3 = sPk[w][t + 3 < TT ? t + 3 : TT - 1];
    const unsigned pk = __builtin_amdgcn_readfirstlane(p0);

    // capture carry-in (s,r) into lane (t&63)
    const int cur = s | (r << 8);
    if (lane == (t & 63)) myv = cur;

    int act, ns;
    if (pk >> 24) {  // forced: no lookup needed
      act = (pk >> 8) & 63;
      ns = (pk >> 16) & 63;
    } else {
      int li;
      asm("v_mov_b32 %0, %1"
          : "=v"(li)
          : "r"((int)((s * 32 + r) * 128) + (int)(pk & 127)));
      const int lv = lut[li];  // vector load, vmcnt-tracked, L2-hot
      act = __builtin_amdgcn_readfirstlane(lv & 63);
      ns = __builtin_amdgcn_readfirstlane((lv >> 6) & 63);
    }

    const bool ispush = act >= 2;
    int npn = ptr + (ispush ? 1 : 0) - (act == 1 ? 1 : 0);
    npn = npn < 0 ? 0 : (npn > 63 ? 63 : npn);
    if (ispush && lane == npn) stackv = act - 2;
    r = __builtin_amdgcn_readlane(stackv, npn);
    ptr = npn;
    s = ns;

    if ((t & 63) == 63)  // off-chain scatter store, [t][b] layout
      traj[((t & ~63) + lane) * BB + b] = (u16)myv;

    p0 = p1; p1 = p2; p2 = p3;
  }
}

// ---- phase 2: materialize all logits. 4096 blocks x 256t = 16384 waves,
// 16 contiguous rows/wave; traj[t][b] -> 32B contiguous scalar reads.
__global__ __launch_bounds__(256) void sm_phase2(
    const int* __restrict__ x, const u16* __restrict__ traj,
    const float* __restrict__ Wm, const float* __restrict__ Wb,
    const float* __restrict__ Ws,
    const float* __restrict__ Mm32, const float* __restrict__ Ms32,
    const float* __restrict__ Mb32, float* __restrict__ out) {
  const int tid = threadIdx.x;
  const int lane = tid & 63;
  const int wid = blockIdx.x * 4 + (tid >> 6);   // 16384 waves
  float* outLM = out;                                  // [T,B,34]
  float* outLB = out + (size_t)TT * BB * NMm;          // [T,B,128]
  float* outLS = out + (size_t)TT * BB * (NMm + NBb);  // [T,B,64]

  const int row0 = wid * 16;
#pragma unroll 2
  for (int k = 0; k < 16; ++k) {
    const int row = row0 + k;
    const int xv = x[row];            // wave-uniform -> scalar load
    const int pr = traj[row];         // [t][b] == flat row  (contiguous)
    const int s = pr & 255;
    const int r = pr >> 8;
    const int rs = 128 + s, rr = 192 + r;
    if (lane < NMm)
      outLM[(size_t)row * NMm + lane] =
          Mm32[xv * NMm + lane] + Wm[rs * NMm + lane] + Wm[rr * NMm + lane];
    outLS[(size_t)row * NSs + lane] =
        Ms32[xv * NSs + lane] + Ws[rs * NSs + lane] + Ws[rr * NSs + lane];
    const f2 mb  = *(const f2*)&Mb32[xv * NBb + 2 * lane];
    const f2 wbs = *(const f2*)&Wb[rs * NBb + 2 * lane];
    const f2 wbr = *(const f2*)&Wb[rr * NBb + 2 * lane];
    f2 o;
    o.x = mb.x + wbs.x + wbr.x;   // same per-element add order as r14/r15
    o.y = mb.y + wbs.y + wbr.y;
    *(f2*)&outLB[(size_t)row * NBb + 2 * lane] = o;
  }
}

extern "C" void kernel_launch(void* const* d_in, const int* in_sizes, int n_in,
                              void* d_out, int out_size, void* d_ws, size_t ws_size,
                              hipStream_t stream) {
  if (ws_size < 1214464) return;  // signature: absmax 0.3457 -> ws too small

  const int* x     = (const int*)d_in[0];
  const int* tactp = (const int*)d_in[1];
  const int* tstp  = (const int*)d_in[2];
  const int* forcp = (const int*)d_in[3];
  const float* embed = (const float*)d_in[4];
  const float* Wm = (const float*)d_in[5];
  const float* bm = (const float*)d_in[6];
  const float* Wb = (const float*)d_in[7];
  const float* bb = (const float*)d_in[8];
  const float* Ws = (const float*)d_in[9];
  const float* bs = (const float*)d_in[10];

  char* wsp = (char*)d_ws;
  float* Mm32 = (float*)(wsp);            //  17408 B
  float* Ms32 = (float*)(wsp + 17408);    //  32768 B
  float* Mb32 = (float*)(wsp + 50176);    //  65536 B
  float* MmT  = (float*)(wsp + 115712);   //  17408 B
  float* MsT  = (float*)(wsp + 133120);   //  32768 B
  u16*   lut  = (u16*)(wsp + 165888);     // 524288 B
  u16*   traj = (u16*)(wsp + 690176);     // 524288 B -> total 1214464 B

  precompute_M<<<128, 256, 0, stream>>>(embed, Wm, bm, Wb, bb, Ws, bs,
                                        Mm32, Ms32, Mb32, MmT, MsT);
  build_lut<<<2048, 128, 0, stream>>>(Wm, Ws, MmT, MsT, lut);
  sm_phase1<<<128, 256, 0, stream>>>(x, tactp, tstp, forcp, lut, traj);
  sm_phase2<<<4096, 256, 0, stream>>>(x, traj, Wm, Wb, Ws,
                                      Mm32, Ms32, Mb32, (float*)d_out);
}

// Round 17
// 191.913 us; speedup vs baseline: 1.1877x; 1.0491x over previous
//
#include <hip/hip_runtime.h>
#include <stdint.h>
#include <limits.h>

// StackMachineCell — LUT design (round 17).
// Ledger r13-r16: ph1_LUT ~125-135us (just under the 132us memset visibility
// threshold) is the dominant component; its ~610cy/step vs ~180cy model is
// attributed to scalar<->vector round-trips on the chain (2x readfirstlane on
// the LUT value, readlane for stack top, branch-bit rfl). This round: the
// recurrence state lives entirely in VGPRs; stack-top via ds_bpermute (VGPR
// index); vector extracts; only the forced-branch bit is scalar (hoistable).
// LUT contents / update rule / traj layout / phase2 / precompute unchanged ->
// absmax must stay 0.0009765625.
// ws: Mm32@0 | Ms32@17408 | Mb32@50176 | MmT@115712 | MsT@133120 |
//     lut@165888 | traj@690176  (total 1214464 B; guarded).

#define TT 512
#define BB 512
#define HH 128
#define NSs 64
#define NMm 34
#define NBb 128

typedef unsigned short u16;
typedef float f2 __attribute__((ext_vector_type(2)));

// ---- precompute M tables (f64 accumulate, f32 store; + transposed copies)
__global__ __launch_bounds__(256) void precompute_M(
    const float* __restrict__ embed,
    const float* __restrict__ Wm, const float* __restrict__ bm,
    const float* __restrict__ Wb, const float* __restrict__ bb,
    const float* __restrict__ Ws, const float* __restrict__ bs,
    float* __restrict__ Mm32, float* __restrict__ Ms32,
    float* __restrict__ Mb32, float* __restrict__ MmT,
    float* __restrict__ MsT) {
  __shared__ double e[HH];
  const int v = blockIdx.x;
  const int tid = threadIdx.x;  // 256
  if (tid < HH) e[tid] = (double)embed[v * HH + tid];
  __syncthreads();
  if (tid < NMm) {
    const int j = tid;
    double acc = 0.0;
    for (int h = 0; h < HH; ++h) acc += e[h] * (double)Wm[h * NMm + j];
    const float r = (float)(acc + (double)bm[j]);
    Mm32[v * NMm + j] = r;
    MmT[j * 128 + v] = r;
  } else if (tid < NMm + NSs) {
    const int j = tid - NMm;
    double acc = 0.0;
    for (int h = 0; h < HH; ++h) acc += e[h] * (double)Ws[h * NSs + j];
    const float r = (float)(acc + (double)bs[j]);
    Ms32[v * NSs + j] = r;
    MsT[j * 128 + v] = r;
  } else if (tid < NMm + NSs + NBb) {
    const int j = tid - NMm - NSs;
    double acc = 0.0;
    for (int h = 0; h < HH; ++h) acc += e[h] * (double)Wb[h * NBb + j];
    Mb32[v * NBb + j] = (float)(acc + (double)bb[j]);
  }
}

// ---- build decision LUT: block = (s,r) pair, thread = v. Coalesced reads
// from transposed tables; arithmetic bit-identical to r12-r16.
__global__ __launch_bounds__(128) void build_lut(
    const float* __restrict__ Wm, const float* __restrict__ Ws,
    const float* __restrict__ MmT, const float* __restrict__ MsT,
    u16* __restrict__ lut) {
  __shared__ float wms[NMm], wmr[NMm], wss[NSs], wsr[NSs];  // 784 B
  const int s = blockIdx.x >> 5;    // 0..63
  const int r = blockIdx.x & 31;    // 0..31
  const int tid = threadIdx.x;      // 128 = one v per thread
  if (tid < NMm) {
    wms[tid] = Wm[(128 + s) * NMm + tid];
    wmr[tid] = Wm[(192 + r) * NMm + tid];
  }
  if (tid < NSs) {
    wss[tid] = Ws[(128 + s) * NSs + tid];
    wsr[tid] = Ws[(192 + r) * NSs + tid];
  }
  __syncthreads();

  const int v = tid;
  int bestm = INT_MIN, act = 0;
#pragma unroll
  for (int j = 0; j < NMm; ++j) {
    const double val = (double)MmT[j * 128 + v] + (double)wms[j] + (double)wmr[j];
    const int iv = (int)(val * 67108864.0);
    if (iv > bestm) { bestm = iv; act = j; }
  }
  int bests = INT_MIN, ns = 0;
#pragma unroll
  for (int j = 0; j < NSs; ++j) {
    const double val = (double)MsT[j * 128 + v] + (double)wss[j] + (double)wsr[j];
    const int iv = (int)(val * 67108864.0);
    if (iv > bests) { bests = iv; ns = j; }
  }
  lut[(unsigned)blockIdx.x * 128 + v] = (u16)(act | (ns << 6));
}

// ---- phase 1: trajectory via LUT, ALL-VECTOR chain. 128 blocks x 256t
// (4 chains/block, 1 chain/wave). Only the forced-branch bit touches the
// scalar engine (hoistable: p0 known 3 iterations ahead).
__global__ __launch_bounds__(256) void sm_phase1(
    const int* __restrict__ x, const int* __restrict__ tact,
    const int* __restrict__ tstate, const int* __restrict__ forc,
    const u16* __restrict__ lut, u16* __restrict__ traj) {
  __shared__ unsigned int sPk[4][TT];  // 8192 B
  const int tid = threadIdx.x;
  const int base = blockIdx.x * 4;
  for (int i = tid; i < 4 * TT; i += 256) {
    const int w = i >> 9, t = i & (TT - 1);
    const int g = t * BB + base + w;
    sPk[w][t] = (unsigned)x[g] | ((unsigned)tact[g] << 8) |
                ((unsigned)tstate[g] << 16) | ((unsigned)forc[g] << 24);
  }
  __syncthreads();

  const int lane = tid & 63;
  const int w = tid >> 6;
  const int b = base + w;

  int stackv = 0;  // lane i holds stack[i] (VGPR)
  int ptr = 0, r = 0, s = 0;   // all VGPR (uniform-valued)
  int myv = 0;                 // lane-rotated traj capture

  unsigned p0 = sPk[w][0], p1 = sPk[w][1], p2 = sPk[w][2];

  for (int t = 0; t < TT; ++t) {
    const unsigned p3 = sPk[w][t + 3 < TT ? t + 3 : TT - 1];
    const unsigned pk_s = __builtin_amdgcn_readfirstlane(p0);  // branch only

    // capture carry-in (s,r) into lane (t&63) — off-chain
    if (lane == (t & 63)) myv = s | (r << 8);

    int act, ns;
    if (pk_s >> 24) {  // forced: no lookup; extract from VGPR p0
      act = (int)((p0 >> 8) & 63u);
      ns  = (int)((p0 >> 16) & 63u);
    } else {
      const int idx = s * 4096 + r * 128 + (int)(p0 & 127u);  // VGPR math
      const int lv = lut[idx];   // vector load, L2-hot
      act = lv & 63;
      ns = (lv >> 6) & 63;
    }

    const bool ispush = act >= 2;
    int npn = ptr + (ispush ? 1 : 0) - (act == 1 ? 1 : 0);
    npn = npn < 0 ? 0 : (npn > 63 ? 63 : npn);
    if (ispush && lane == npn) stackv = act - 2;
    r = __builtin_amdgcn_ds_bpermute(npn * 4, stackv);  // VGPR index
    ptr = npn;
    s = ns;

    if ((t & 63) == 63)  // off-chain scatter store, [t][b] layout
      traj[((t & ~63) + lane) * BB + b] = (u16)myv;

    p0 = p1; p1 = p2; p2 = p3;
  }
}

// ---- phase 2: materialize all logits. 4096 blocks x 256t = 16384 waves,
// 16 contiguous rows/wave; traj[t][b] -> 32B contiguous scalar reads.
__global__ __launch_bounds__(256) void sm_phase2(
    const int* __restrict__ x, const u16* __restrict__ traj,
    const float* __restrict__ Wm, const float* __restrict__ Wb,
    const float* __restrict__ Ws,
    const float* __restrict__ Mm32, const float* __restrict__ Ms32,
    const float* __restrict__ Mb32, float* __restrict__ out) {
  const int tid = threadIdx.x;
  const int lane = tid & 63;
  const int wid = blockIdx.x * 4 + (tid >> 6);   // 16384 waves
  float* outLM = out;                                  // [T,B,34]
  float* outLB = out + (size_t)TT * BB * NMm;          // [T,B,128]
  float* outLS = out + (size_t)TT * BB * (NMm + NBb);  // [T,B,64]

  const int row0 = wid * 16;
#pragma unroll 2
  for (int k = 0; k < 16; ++k) {
    const int row = row0 + k;
    const int xv = x[row];            // wave-uniform -> scalar load
    const int pr = traj[row];         // [t][b] == flat row  (contiguous)
    const int s = pr & 255;
    const int r = pr >> 8;
    const int rs = 128 + s, rr = 192 + r;
    if (lane < NMm)
      outLM[(size_t)row * NMm + lane] =
          Mm32[xv * NMm + lane] + Wm[rs * NMm + lane] + Wm[rr * NMm + lane];
    outLS[(size_t)row * NSs + lane] =
        Ms32[xv * NSs + lane] + Ws[rs * NSs + lane] + Ws[rr * NSs + lane];
    const f2 mb  = *(const f2*)&Mb32[xv * NBb + 2 * lane];
    const f2 wbs = *(const f2*)&Wb[rs * NBb + 2 * lane];
    const f2 wbr = *(const f2*)&Wb[rr * NBb + 2 * lane];
    f2 o;
    o.x = mb.x + wbs.x + wbr.x;   // same per-element add order as r14-r16
    o.y = mb.y + wbs.y + wbr.y;
    *(f2*)&outLB[(size_t)row * NBb + 2 * lane] = o;
  }
}

extern "C" void kernel_launch(void* const* d_in, const int* in_sizes, int n_in,
                              void* d_out, int out_size, void* d_ws, size_t ws_size,
                              hipStream_t stream) {
  if (ws_size < 1214464) return;  // signature: absmax 0.3457 -> ws too small

  const int* x     = (const int*)d_in[0];
  const int* tactp = (const int*)d_in[1];
  const int* tstp  = (const int*)d_in[2];
  const int* forcp = (const int*)d_in[3];
  const float* embed = (const float*)d_in[4];
  const float* Wm = (const float*)d_in[5];
  const float* bm = (const float*)d_in[6];
  const float* Wb = (const float*)d_in[7];
  const float* bb = (const float*)d_in[8];
  const float* Ws = (const float*)d_in[9];
  const float* bs = (const float*)d_in[10];

  char* wsp = (char*)d_ws;
  float* Mm32 = (float*)(wsp);            //  17408 B
  float* Ms32 = (float*)(wsp + 17408);    //  32768 B
  float* Mb32 = (float*)(wsp + 50176);    //  65536 B
  float* MmT  = (float*)(wsp + 115712);   //  17408 B
  float* MsT  = (float*)(wsp + 133120);   //  32768 B
  u16*   lut  = (u16*)(wsp + 165888);     // 524288 B
  u16*   traj = (u16*)(wsp + 690176);     // 524288 B -> total 1214464 B

  precompute_M<<<128, 256, 0, stream>>>(embed, Wm, bm, Wb, bb, Ws, bs,
                                        Mm32, Ms32, Mb32, MmT, MsT);
  build_lut<<<2048, 128, 0, stream>>>(Wm, Ws, MmT, MsT, lut);
  sm_phase1<<<128, 256, 0, stream>>>(x, tactp, tstp, forcp, lut, traj);
  sm_phase2<<<4096, 256, 0, stream>>>(x, traj, Wm, Wb, Ws,
                                      Mm32, Ms32, Mb32, (float*)d_out);
}

// Round 18
// 190.599 us; speedup vs baseline: 1.1959x; 1.0069x over previous
//
#include <hip/hip_runtime.h>
#include <stdint.h>
#include <limits.h>

// StackMachineCell — LUT design (round 18).
// Ledger r14-r17: phase1 ~115-125us (~560 cy/step) dominated by the serial
// per-step L2 LUT load (~230cy) + in-order issue at 1 wave/SIMD. v_t is
// known in advance, so re-index LUT as lutV[v][s*32+r] and prefetch the 4KB
// slice for step t+2 into a per-wave LDS double-buffer via global_load_lds
// (width 16, per-lane source + wave-uniform dest, m97 pattern). Dependent
// access becomes ds_read_u16 (~120cy, same-address broadcast). Stack top via
// readfirstlane+readlane (~15cy) instead of ds_bpermute (~60cy).
// LUT bits / update rule / traj layout / phase2 / precompute unchanged ->
// absmax must stay 0.0009765625. Diverged-trajectory absmax (~0.5) would
// indict the glds slice path.
// ws: Mm32@0 | Ms32@17408 | Mb32@50176 | MmT@115712 | MsT@133120 |
//     lutV@165888 | traj@690176  (total 1214464 B; guarded).

#define TT 512
#define BB 512
#define HH 128
#define NSs 64
#define NMm 34
#define NBb 128

typedef unsigned short u16;
typedef float f2 __attribute__((ext_vector_type(2)));

// ---- precompute M tables (f64 accumulate, f32 store; + transposed copies)
__global__ __launch_bounds__(256) void precompute_M(
    const float* __restrict__ embed,
    const float* __restrict__ Wm, const float* __restrict__ bm,
    const float* __restrict__ Wb, const float* __restrict__ bb,
    const float* __restrict__ Ws, const float* __restrict__ bs,
    float* __restrict__ Mm32, float* __restrict__ Ms32,
    float* __restrict__ Mb32, float* __restrict__ MmT,
    float* __restrict__ MsT) {
  __shared__ double e[HH];
  const int v = blockIdx.x;
  const int tid = threadIdx.x;  // 256
  if (tid < HH) e[tid] = (double)embed[v * HH + tid];
  __syncthreads();
  if (tid < NMm) {
    const int j = tid;
    double acc = 0.0;
    for (int h = 0; h < HH; ++h) acc += e[h] * (double)Wm[h * NMm + j];
    const float r = (float)(acc + (double)bm[j]);
    Mm32[v * NMm + j] = r;
    MmT[j * 128 + v] = r;
  } else if (tid < NMm + NSs) {
    const int j = tid - NMm;
    double acc = 0.0;
    for (int h = 0; h < HH; ++h) acc += e[h] * (double)Ws[h * NSs + j];
    const float r = (float)(acc + (double)bs[j]);
    Ms32[v * NSs + j] = r;
    MsT[j * 128 + v] = r;
  } else if (tid < NMm + NSs + NBb) {
    const int j = tid - NMm - NSs;
    double acc = 0.0;
    for (int h = 0; h < HH; ++h) acc += e[h] * (double)Wb[h * NBb + j];
    Mb32[v * NBb + j] = (float)(acc + (double)bb[j]);
  }
}

// ---- build decision LUT: block = (s,r) pair, thread = v. Coalesced reads
// from transposed tables; arithmetic bit-identical to r12-r17. Output in
// v-major layout lutV[v*2048 + s*32 + r] (scatter write, off-critical).
__global__ __launch_bounds__(128) void build_lut(
    const float* __restrict__ Wm, const float* __restrict__ Ws,
    const float* __restrict__ MmT, const float* __restrict__ MsT,
    u16* __restrict__ lutV) {
  __shared__ float wms[NMm], wmr[NMm], wss[NSs], wsr[NSs];  // 784 B
  const int s = blockIdx.x >> 5;    // 0..63
  const int r = blockIdx.x & 31;    // 0..31
  const int tid = threadIdx.x;      // 128 = one v per thread
  if (tid < NMm) {
    wms[tid] = Wm[(128 + s) * NMm + tid];
    wmr[tid] = Wm[(192 + r) * NMm + tid];
  }
  if (tid < NSs) {
    wss[tid] = Ws[(128 + s) * NSs + tid];
    wsr[tid] = Ws[(192 + r) * NSs + tid];
  }
  __syncthreads();

  const int v = tid;
  int bestm = INT_MIN, act = 0;
#pragma unroll
  for (int j = 0; j < NMm; ++j) {
    const double val = (double)MmT[j * 128 + v] + (double)wms[j] + (double)wmr[j];
    const int iv = (int)(val * 67108864.0);
    if (iv > bestm) { bestm = iv; act = j; }
  }
  int bests = INT_MIN, ns = 0;
#pragma unroll
  for (int j = 0; j < NSs; ++j) {
    const double val = (double)MsT[j * 128 + v] + (double)wss[j] + (double)wsr[j];
    const int iv = (int)(val * 67108864.0);
    if (iv > bests) { bests = iv; ns = j; }
  }
  lutV[(unsigned)v * 2048 + (unsigned)blockIdx.x] = (u16)(act | (ns << 6));
}

// ---- phase 1: trajectory via LDS-staged LUT slices. 128 blocks x 256t
// (4 chains/block, 1 chain/wave). Slice for step t in sSlice[w][t&1];
// prefetched 2 steps ahead with global_load_lds (issued AFTER the current
// step's ds_read value is consumed -> wave-serial ordering is safe).
__global__ __launch_bounds__(256) void sm_phase1(
    const int* __restrict__ x, const int* __restrict__ tact,
    const int* __restrict__ tstate, const int* __restrict__ forc,
    const u16* __restrict__ lutV, u16* __restrict__ traj) {
  __shared__ unsigned int sPk[4][TT];   //  8192 B
  __shared__ u16 sSlice[4][2][2048];    // 32768 B (4 waves x dbuf x 4KB)
  const int tid = threadIdx.x;
  const int base = blockIdx.x * 4;
  for (int i = tid; i < 4 * TT; i += 256) {
    const int w = i >> 9, t = i & (TT - 1);
    const int g = t * BB + base + w;
    sPk[w][t] = (unsigned)x[g] | ((unsigned)tact[g] << 8) |
                ((unsigned)tstate[g] << 16) | ((unsigned)forc[g] << 24);
  }
  __syncthreads();

  const int lane = tid & 63;
  const int w = tid >> 6;
  const int b = base + w;
  const char* lutB = (const char*)lutV;

  int stackv = 0;  // lane i holds stack[i]
  int ptr = 0, rr = 0, s = 0;
  int myv = 0;     // lane-rotated traj capture

  unsigned p0 = sPk[w][0], p1 = sPk[w][1], p2 = sPk[w][2];

  // prologue: slices for t=0 (buf0) and t=1 (buf1)
#pragma unroll
  for (int q = 0; q < 4; ++q) {
    const char* g0 = lutB + (((size_t)(p0 & 127u)) << 12) + (q << 10) + (lane << 4);
    __builtin_amdgcn_global_load_lds(
        (const __attribute__((address_space(1))) unsigned int*)g0,
        (__attribute__((address_space(3))) unsigned int*)&sSlice[w][0][q * 512],
        16, 0, 0);
  }
#pragma unroll
  for (int q = 0; q < 4; ++q) {
    const char* g1 = lutB + (((size_t)(p1 & 127u)) << 12) + (q << 10) + (lane << 4);
    __builtin_amdgcn_global_load_lds(
        (const __attribute__((address_space(1))) unsigned int*)g1,
        (__attribute__((address_space(3))) unsigned int*)&sSlice[w][1][q * 512],
        16, 0, 0);
  }

  for (int t = 0; t < TT; ++t) {
    const unsigned p3 = sPk[w][t + 3 < TT ? t + 3 : TT - 1];
    const unsigned pk_s = __builtin_amdgcn_readfirstlane(p0);

    // capture carry-in (s,r) into lane (t&63) — off-chain
    if (lane == (t & 63)) myv = s | (rr << 8);

    int act, ns;
    if (pk_s >> 24) {  // forced: no lookup; extract from VGPR p0
      act = (int)((p0 >> 8) & 63u);
      ns  = (int)((p0 >> 16) & 63u);
    } else {
      const int lv = sSlice[w][t & 1][s * 32 + rr];  // ds_read_u16, broadcast
      act = lv & 63;
      ns = (lv >> 6) & 63;
    }

    // prefetch slice for t+2 into buf[t&1] (after the read's value is used)
#pragma unroll
    for (int q = 0; q < 4; ++q) {
      const char* g = lutB + (((size_t)(p2 & 127u)) << 12) + (q << 10) + (lane << 4);
      __builtin_amdgcn_global_load_lds(
          (const __attribute__((address_space(1))) unsigned int*)g,
          (__attribute__((address_space(3))) unsigned int*)&sSlice[w][t & 1][q * 512],
          16, 0, 0);
    }

    const bool ispush = act >= 2;
    int npn = ptr + (ispush ? 1 : 0) - (act == 1 ? 1 : 0);
    npn = npn < 0 ? 0 : (npn > 63 ? 63 : npn);
    if (ispush && lane == npn) stackv = act - 2;
    const int npn_s = __builtin_amdgcn_readfirstlane(npn);
    rr = __builtin_amdgcn_readlane(stackv, npn_s);
    ptr = npn;
    s = ns;

    if ((t & 63) == 63)  // off-chain scatter store, [t][b] layout
      traj[((t & ~63) + lane) * BB + b] = (u16)myv;

    p0 = p1; p1 = p2; p2 = p3;
  }
}

// ---- phase 2: materialize all logits. 4096 blocks x 256t = 16384 waves,
// 16 contiguous rows/wave; traj[t][b] -> 32B contiguous scalar reads.
__global__ __launch_bounds__(256) void sm_phase2(
    const int* __restrict__ x, const u16* __restrict__ traj,
    const float* __restrict__ Wm, const float* __restrict__ Wb,
    const float* __restrict__ Ws,
    const float* __restrict__ Mm32, const float* __restrict__ Ms32,
    const float* __restrict__ Mb32, float* __restrict__ out) {
  const int tid = threadIdx.x;
  const int lane = tid & 63;
  const int wid = blockIdx.x * 4 + (tid >> 6);   // 16384 waves
  float* outLM = out;                                  // [T,B,34]
  float* outLB = out + (size_t)TT * BB * NMm;          // [T,B,128]
  float* outLS = out + (size_t)TT * BB * (NMm + NBb);  // [T,B,64]

  const int row0 = wid * 16;
#pragma unroll 2
  for (int k = 0; k < 16; ++k) {
    const int row = row0 + k;
    const int xv = x[row];            // wave-uniform -> scalar load
    const int pr = traj[row];         // [t][b] == flat row  (contiguous)
    const int s = pr & 255;
    const int r = pr >> 8;
    const int rs = 128 + s, rr = 192 + r;
    if (lane < NMm)
      outLM[(size_t)row * NMm + lane] =
          Mm32[xv * NMm + lane] + Wm[rs * NMm + lane] + Wm[rr * NMm + lane];
    outLS[(size_t)row * NSs + lane] =
        Ms32[xv * NSs + lane] + Ws[rs * NSs + lane] + Ws[rr * NSs + lane];
    const f2 mb  = *(const f2*)&Mb32[xv * NBb + 2 * lane];
    const f2 wbs = *(const f2*)&Wb[rs * NBb + 2 * lane];
    const f2 wbr = *(const f2*)&Wb[rr * NBb + 2 * lane];
    f2 o;
    o.x = mb.x + wbs.x + wbr.x;   // same per-element add order as r14-r17
    o.y = mb.y + wbs.y + wbr.y;
    *(f2*)&outLB[(size_t)row * NBb + 2 * lane] = o;
  }
}

extern "C" void kernel_launch(void* const* d_in, const int* in_sizes, int n_in,
                              void* d_out, int out_size, void* d_ws, size_t ws_size,
                              hipStream_t stream) {
  if (ws_size < 1214464) return;  // signature: absmax 0.3457 -> ws too small

  const int* x     = (const int*)d_in[0];
  const int* tactp = (const int*)d_in[1];
  const int* tstp  = (const int*)d_in[2];
  const int* forcp = (const int*)d_in[3];
  const float* embed = (const float*)d_in[4];
  const float* Wm = (const float*)d_in[5];
  const float* bm = (const float*)d_in[6];
  const float* Wb = (const float*)d_in[7];
  const float* bb = (const float*)d_in[8];
  const float* Ws = (const float*)d_in[9];
  const float* bs = (const float*)d_in[10];

  char* wsp = (char*)d_ws;
  float* Mm32 = (float*)(wsp);            //  17408 B
  float* Ms32 = (float*)(wsp + 17408);    //  32768 B
  float* Mb32 = (float*)(wsp + 50176);    //  65536 B
  float* MmT  = (float*)(wsp + 115712);   //  17408 B
  float* MsT  = (float*)(wsp + 133120);   //  32768 B
  u16*   lutV = (u16*)(wsp + 165888);     // 524288 B
  u16*   traj = (u16*)(wsp + 690176);     // 524288 B -> total 1214464 B

  precompute_M<<<128, 256, 0, stream>>>(embed, Wm, bm, Wb, bb, Ws, bs,
                                        Mm32, Ms32, Mb32, MmT, MsT);
  build_lut<<<2048, 128, 0, stream>>>(Wm, Ws, MmT, MsT, lutV);
  sm_phase1<<<128, 256, 0, stream>>>(x, tactp, tstp, forcp, lutV, traj);
  sm_phase2<<<4096, 256, 0, stream>>>(x, traj, Wm, Wb, Ws,
                                      Mm32, Ms32, Mb32, (float*)d_out);
}